// Round 16
// baseline (2987.375 us; speedup 1.0000x reference)
//
#include <hip/hip_runtime.h>
#include <hip/hip_bf16.h>

typedef __attribute__((ext_vector_type(8))) short short8;
typedef __attribute__((ext_vector_type(4))) short short4v;
typedef __attribute__((ext_vector_type(4))) float floatx4;

#define GLD16(g, l) __builtin_amdgcn_global_load_lds( \
    (__attribute__((address_space(1))) void*)(g),      \
    (__attribute__((address_space(3))) void*)(l), 16, 0, 0)

#define MFMA_BF16(a, b, c) __builtin_amdgcn_mfma_f32_16x16x32_bf16((a), (b), (c), 0, 0, 0)

__device__ __forceinline__ short f2bf(float f) {
  union { __hip_bfloat16 h; short s; } u;
  u.h = __float2bfloat16(f);
  return u.s;
}

template <int N>
__device__ __forceinline__ void wait_vm() {
  if constexpr (N == 0) asm volatile("s_waitcnt vmcnt(0)" ::: "memory");
  else if constexpr (N == 2) asm volatile("s_waitcnt vmcnt(2)" ::: "memory");
}
__device__ __forceinline__ void cfence() { asm volatile("" ::: "memory"); }

// ---------------------------------------------------------------------------
// transpose + fp32->bf16 convert:  in fp32 [K][N] -> out bf16 [Npad][K]
// ---------------------------------------------------------------------------
__global__ __launch_bounds__(256)
void transpose_convert(const float* __restrict__ in, short* __restrict__ out,
                       const int K, const int N, const size_t inStride,
                       const size_t outStride) {
  in += blockIdx.z * inStride;
  out += blockIdx.z * outStride;
  __shared__ float tile[32][33];
  const int n0 = blockIdx.x * 32;
  const int k0 = blockIdx.y * 32;
  const int tx = threadIdx.x;
  const int ty = threadIdx.y;
#pragma unroll
  for (int i = 0; i < 4; ++i) {
    const int kk = ty + i * 8;
    const int nn = n0 + tx;
    tile[kk][tx] = (nn < N) ? in[(size_t)(k0 + kk) * N + nn] : 0.f;
  }
  __syncthreads();
#pragma unroll
  for (int i = 0; i < 4; ++i) {
    const int nn = ty + i * 8;
    out[(size_t)(n0 + nn) * K + k0 + tx] = f2bf(tile[tx][nn]);
  }
}

// ---------------------------------------------------------------------------
__global__ __launch_bounds__(256)
void embed_kernel(const int* __restrict__ idx, const float* __restrict__ wte,
                  const float* __restrict__ wpe, float* __restrict__ x) {
  const int row = blockIdx.x;
  const int tok = idx[row];
  const int s = row & 1023;
  const float* wt = wte + (size_t)tok * 768;
  const float* wp = wpe + (size_t)s * 768;
  float* xr = x + (size_t)row * 768;
  for (int c = threadIdx.x; c < 768; c += 256) xr[c] = wt[c] + wp[c];
}

// ---------------------------------------------------------------------------
// layernorm: wave-per-row (4 rows/block), shuffle-only, short4 bf16 stores.
// ---------------------------------------------------------------------------
__global__ __launch_bounds__(256)
void ln_kernel(const float* __restrict__ x, const float* __restrict__ g,
               const float* __restrict__ b, short* __restrict__ out) {
  const int wv = threadIdx.x >> 6, lane = threadIdx.x & 63;
  const int row = blockIdx.x * 4 + wv;
  const float* xr = x + (size_t)row * 768 + lane * 12;
  const float4 a0 = *(const float4*)(xr);
  const float4 a1 = *(const float4*)(xr + 4);
  const float4 a2 = *(const float4*)(xr + 8);
  float v[12] = {a0.x, a0.y, a0.z, a0.w, a1.x, a1.y, a1.z, a1.w,
                 a2.x, a2.y, a2.z, a2.w};
  float s = 0.f;
#pragma unroll
  for (int i = 0; i < 12; ++i) s += v[i];
#pragma unroll
  for (int m = 1; m < 64; m <<= 1) s += __shfl_xor(s, m);
  const float mean = s * (1.0f / 768.0f);
  float q = 0.f;
#pragma unroll
  for (int i = 0; i < 12; ++i) {
    v[i] -= mean;
    q += v[i] * v[i];
  }
#pragma unroll
  for (int m = 1; m < 64; m <<= 1) q += __shfl_xor(q, m);
  const float inv = rsqrtf(q * (1.0f / 768.0f) + 1e-5f);

  const float* gp = g + lane * 12;
  const float* bp = b + lane * 12;
  const float4 g0 = *(const float4*)(gp);
  const float4 g1 = *(const float4*)(gp + 4);
  const float4 g2 = *(const float4*)(gp + 8);
  const float4 b0 = *(const float4*)(bp);
  const float4 b1 = *(const float4*)(bp + 4);
  const float4 b2 = *(const float4*)(bp + 8);
  const float gg[12] = {g0.x, g0.y, g0.z, g0.w, g1.x, g1.y, g1.z, g1.w,
                        g2.x, g2.y, g2.z, g2.w};
  const float bb[12] = {b0.x, b0.y, b0.z, b0.w, b1.x, b1.y, b1.z, b1.w,
                        b2.x, b2.y, b2.z, b2.w};
  short r[12];
#pragma unroll
  for (int i = 0; i < 12; ++i) r[i] = f2bf(v[i] * inv * gg[i] + bb[i]);
  short* orow = out + (size_t)row * 768 + lane * 12;
#pragma unroll
  for (int i = 0; i < 3; ++i)
    *(short4v*)(orow + i * 4) = short4v{r[i * 4], r[i * 4 + 1], r[i * 4 + 2],
                                        r[i * 4 + 3]};
}

// ---------------------------------------------------------------------------
// Layer GEMM (r12-proven): BMxBN, BK=64, unit-XOR swizzle, dbuf with
// implicit __syncthreads, hoisted incrementing stage pointers.
// ---------------------------------------------------------------------------
enum { EPI_QKV = 0, EPI_RESID = 1, EPI_GELU = 2 };

template <int BM, int BN, int EPI>
__global__ __launch_bounds__(256)
void gemm_kernel(const short* __restrict__ A, const short* __restrict__ Bt,
                 const int K,
                 const float* __restrict__ bias0, const float* __restrict__ bias1,
                 const float* __restrict__ bias2, float* __restrict__ fout,
                 short* __restrict__ bout0, short* __restrict__ bout1,
                 short* __restrict__ bout2) {
  constexpr int MF = BM / 32;
  constexpr int NF = BN / 32;
  __shared__ short sA[2][BM * 64];
  __shared__ short sB[2][BN * 64];
  const int tid = threadIdx.x;
  const int wv = tid >> 6;
  const int lane = tid & 63;
  const int lrow = lane & 15;
  const int lk8 = lane >> 4;
  const int m0 = blockIdx.x * BM;
  const int n0 = blockIdx.y * BN;
  const int wm = (wv >> 1) * (BM / 2);
  const int wn = (wv & 1) * (BN / 2);
  constexpr int MW = BM / 2 / 16;
  constexpr int NW = BN / 2 / 16;

  floatx4 acc[MW][NW];
#pragma unroll
  for (int m = 0; m < MW; ++m)
#pragma unroll
    for (int n = 0; n < NW; ++n) acc[m][n] = {0.f, 0.f, 0.f, 0.f};

  const short* pA[MF];
  const short* pB[NF];
#pragma unroll
  for (int i = 0; i < MF; ++i) {
    const int p = i * 256 + tid;
    const int rr = p >> 3, up = p & 7;
    pA[i] = A + (size_t)(m0 + rr) * K + ((up ^ (rr & 7)) << 3);
  }
#pragma unroll
  for (int i = 0; i < NF; ++i) {
    const int p = i * 256 + tid;
    const int rr = p >> 3, up = p & 7;
    pB[i] = Bt + (size_t)(n0 + rr) * K + ((up ^ (rr & 7)) << 3);
  }

  auto stage = [&](int buf) {
#pragma unroll
    for (int i = 0; i < MF; ++i) {
      GLD16(pA[i], sA[buf] + (i * 256 + wv * 64) * 8);
      pA[i] += 64;
    }
#pragma unroll
    for (int i = 0; i < NF; ++i) {
      GLD16(pB[i], sB[buf] + (i * 256 + wv * 64) * 8);
      pB[i] += 64;
    }
  };

  auto compute = [&](const short* pa, const short* pb) {
    const int xr = lrow & 7;
    short8 af[MW][2], bv[NW][2];
#pragma unroll
    for (int m = 0; m < MW; ++m) {
      const int row = (wm + m * 16 + lrow) * 64;
      af[m][0] = *(const short8*)(pa + row + ((lk8 ^ xr) << 3));
      af[m][1] = *(const short8*)(pa + row + (((4 + lk8) ^ xr) << 3));
    }
#pragma unroll
    for (int n = 0; n < NW; ++n) {
      const int row = (wn + n * 16 + lrow) * 64;
      bv[n][0] = *(const short8*)(pb + row + ((lk8 ^ xr) << 3));
      bv[n][1] = *(const short8*)(pb + row + (((4 + lk8) ^ xr) << 3));
    }
#pragma unroll
    for (int m = 0; m < MW; ++m)
#pragma unroll
      for (int n = 0; n < NW; ++n) {
        acc[m][n] = MFMA_BF16(af[m][0], bv[n][0], acc[m][n]);
        acc[m][n] = MFMA_BF16(af[m][1], bv[n][1], acc[m][n]);
      }
  };

  const int nk = K >> 6;
  stage(0);
  __syncthreads();
  int cur = 0;
  for (int kt = 0; kt < nk; ++kt) {
    if (kt + 1 < nk) stage(cur ^ 1);
    compute(sA[cur], sB[cur]);
    __syncthreads();
    cur ^= 1;
  }

#pragma unroll
  for (int m = 0; m < MW; ++m) {
#pragma unroll
    for (int n = 0; n < NW; ++n) {
#pragma unroll
      for (int r = 0; r < 4; ++r) {
        const float v = acc[m][n][r];
        const int gm = m0 + wm + m * 16 + lk8 * 4 + r;
        const int gn = n0 + wn + n * 16 + lrow;
        if (EPI == EPI_QKV) {
          const int sec = (gn >= 1536) ? 2 : (gn >= 768 ? 1 : 0);
          const int nn = gn - sec * 768;
          const int hh = nn >> 6, dh = nn & 63;
          const int bb = gm >> 10, srow = gm & 1023;
          if (sec == 0) {
            // q pre-scaled by 0.125 * log2(e) so attention can use exp2
            bout0[(((size_t)(bb * 12 + hh) * 1024 + srow) << 6) + dh] =
                f2bf((v + bias0[nn]) * 0.18033688f);
          } else if (sec == 1) {
            bout1[(((size_t)(bb * 12 + hh) * 1024 + srow) << 6) + dh] =
                f2bf(v + bias1[nn]);
          } else {
            bout2[(((size_t)(bb * 12 + hh) * 64 + dh) << 10) + srow] =
                f2bf(v + bias2[nn]);
          }
        } else if (EPI == EPI_RESID) {
          float* xp = fout + (size_t)gm * 768 + gn;
          *xp = *xp + v + bias0[gn];
        } else {  // EPI_GELU
          const float tt = v + bias0[gn];
          const float gl = 0.5f * tt * (1.f + erff(tt * 0.70710678118654752f));
          bout0[(size_t)gm * 3072 + gn] = f2bf(gl);
        }
      }
    }
  }
}

// ---------------------------------------------------------------------------
// LM-head GEMM — 256x256, 8 waves (2Mx4N), 128KB LDS dbuf, BK=64, counted
// vmcnt. Per K-tile: p0 {issue next-half0; vmcnt(2) [own tile's 8 loads
// landed, 2 in flight]; barrier; ds_read quadrant; MFMA}, p1-p3 {ds_read
// quadrant; issue next-half; MFMA}, end-of-tile barrier (separates reads of
// buf[cur] from kt+1's writes into it). vmcnt(0) only on last tile.
// ---------------------------------------------------------------------------
__global__ __launch_bounds__(512)
void gemm_lm_kernel(const short* __restrict__ A, const short* __restrict__ Bt,
                    float* __restrict__ fout) {
  __shared__ short sA[2][256 * 64];  // 2 x 32 KB
  __shared__ short sB[2][256 * 64];  // 2 x 32 KB
  const int K = 768;
  const int tid = threadIdx.x;
  const int wv = tid >> 6;
  const int lane = tid & 63;
  const int lrow = lane & 15;
  const int lk8 = lane >> 4;
  const int m0 = blockIdx.x * 256;
  const int n0 = blockIdx.y * 256;
  const int wm = (wv >> 2) * 128;  // 2 wave-rows
  const int wn = (wv & 3) * 64;    // 4 wave-cols
  const int xr = lrow & 7;

  floatx4 acc[8][4];
#pragma unroll
  for (int m = 0; m < 8; ++m)
#pragma unroll
    for (int n = 0; n < 4; ++n) acc[m][n] = {0.f, 0.f, 0.f, 0.f};

  // stage pointers: half h {0:A-lo,1:A-hi,2:B-lo,3:B-hi}, 2 loads each
  const short* pH[4][2];
#pragma unroll
  for (int h = 0; h < 4; ++h)
#pragma unroll
    for (int i = 0; i < 2; ++i) {
      const int slot = i * 512 + tid;
      const int rr = (slot >> 3) + (h & 1) * 128;
      const int up = slot & 7;
      const short* gb = (h < 2) ? (A + (size_t)(m0 + rr) * K)
                                : (Bt + (size_t)(n0 + rr) * K);
      pH[h][i] = gb + ((up ^ (rr & 7)) << 3);
    }

  auto stage_half = [&](int buf, int h) {
    short* dst = ((h < 2) ? sA[buf] : sB[buf]) + (h & 1) * 8192;
#pragma unroll
    for (int i = 0; i < 2; ++i) {
      GLD16(pH[h][i], dst + (i * 512 + wv * 64) * 8);
      pH[h][i] += 64;
    }
  };

  // prologue: stage all 4 halves of K-tile 0 into buffer 0 (8 loads/thread)
#pragma unroll
  for (int h = 0; h < 4; ++h) stage_half(0, h);

  int cur = 0;
  for (int kt = 0; kt < 12; ++kt) {
    const short* pa = sA[cur];
    const short* pb = sB[cur];
#pragma unroll
    for (int p = 0; p < 4; ++p) {
      const int mh = p >> 1, nh = p & 1;
      if (kt + 1 < 12) stage_half(cur ^ 1, p);
      if (p == 0) {
        if (kt + 1 < 12) wait_vm<2>();
        else wait_vm<0>();
        __builtin_amdgcn_s_barrier();
        cfence();
      }
      short8 af[4][2], bv[2][2];
#pragma unroll
      for (int mi = 0; mi < 4; ++mi) {
        const int row = (wm + mh * 64 + mi * 16 + lrow) * 64;
        af[mi][0] = *(const short8*)(pa + row + ((lk8 ^ xr) << 3));
        af[mi][1] = *(const short8*)(pa + row + (((4 + lk8) ^ xr) << 3));
      }
#pragma unroll
      for (int ni = 0; ni < 2; ++ni) {
        const int row = (wn + nh * 32 + ni * 16 + lrow) * 64;
        bv[ni][0] = *(const short8*)(pb + row + ((lk8 ^ xr) << 3));
        bv[ni][1] = *(const short8*)(pb + row + (((4 + lk8) ^ xr) << 3));
      }
      __builtin_amdgcn_s_setprio(1);
#pragma unroll
      for (int mi = 0; mi < 4; ++mi)
#pragma unroll
        for (int ni = 0; ni < 2; ++ni) {
          acc[mh * 4 + mi][nh * 2 + ni] =
              MFMA_BF16(af[mi][0], bv[ni][0], acc[mh * 4 + mi][nh * 2 + ni]);
          acc[mh * 4 + mi][nh * 2 + ni] =
              MFMA_BF16(af[mi][1], bv[ni][1], acc[mh * 4 + mi][nh * 2 + ni]);
        }
      __builtin_amdgcn_s_setprio(0);
    }
    cfence();
    __builtin_amdgcn_s_barrier();  // reads of buf[cur] done before reuse
    cfence();
    cur ^= 1;
  }

#pragma unroll
  for (int m = 0; m < 8; ++m)
#pragma unroll
    for (int n = 0; n < 4; ++n)
#pragma unroll
      for (int r = 0; r < 4; ++r) {
        const int gm = m0 + wm + m * 16 + lk8 * 4 + r;
        const int gn = n0 + wn + n * 16 + lrow;
        if (gn < 50257) fout[(size_t)gm * 50257 + gn] = acc[m][n][r];
      }
}

// ---------------------------------------------------------------------------
// flash attention (causal), swapped QK^T + dbuf async-stage + defer-max (r13).
// ---------------------------------------------------------------------------
__global__ __launch_bounds__(256)
void attn_kernel(const short* __restrict__ q, const short* __restrict__ k,
                 const short* __restrict__ vt, short* __restrict__ o) {
  __shared__ short sK[2][64 * 64];
  __shared__ short sV[2][64 * 64];
  const int bh = blockIdx.x;
  const int qi = 15 - blockIdx.y;
  const int tid = threadIdx.x;
  const int wv = tid >> 6, lane = tid & 63;
  const int lrow = lane & 15, lk8 = lane >> 4;
  const int q0 = qi * 64;
  const int qrow = q0 + wv * 16 + lrow;

  const short* qg = q + ((size_t)(bh * 1024 + qrow)) * 64 + lk8 * 8;
  const short8 qf0 = *(const short8*)qg;
  const short8 qf1 = *(const short8*)(qg + 32);

  const int e0 = tid * 8, e1 = (256 + tid) * 8;
  const int sr0 = e0 >> 6, sc0 = e0 & 63;
  const int sr1 = e1 >> 6, sc1 = e1 & 63;
  const int su0 = ((sc0 >> 3) ^ (sr0 & 7)) << 3;
  const int su1 = ((sc1 >> 3) ^ (sr1 & 7)) << 3;
  const short* kb = k + (size_t)bh * 1024 * 64;
  const short* vb = vt + (size_t)bh * 64 * 1024;

  short8 kreg0, kreg1, vreg0, vreg1;
  auto load_tile = [&](int k0) {
    kreg0 = *(const short8*)(kb + (size_t)(k0 + sr0) * 64 + sc0);
    kreg1 = *(const short8*)(kb + (size_t)(k0 + sr1) * 64 + sc1);
    vreg0 = *(const short8*)(vb + (size_t)sr0 * 1024 + k0 + sc0);
    vreg1 = *(const short8*)(vb + (size_t)sr1 * 1024 + k0 + sc1);
  };
  auto write_tile = [&](short* dK, short* dV) {
    *(short8*)(dK + sr0 * 64 + su0) = kreg0;
    *(short8*)(dK + sr1 * 64 + su1) = kreg1;
    *(short8*)(dV + sr0 * 64 + su0) = vreg0;
    *(short8*)(dV + sr1 * 64 + su1) = vreg1;
  };

  float m_run = -1e30f, lsum = 0.f;
  floatx4 accO[4];
#pragma unroll
  for (int n = 0; n < 4; ++n) accO[n] = {0.f, 0.f, 0.f, 0.f};

  load_tile(0);
  write_tile(sK[0], sV[0]);
  __syncthreads();

  int cur = 0;
  for (int t = 0; t <= qi; ++t) {
    const int k0 = t * 64;
    if (t < qi) load_tile(k0 + 64);

    floatx4 accS[4];
#pragma unroll
    for (int n = 0; n < 4; ++n) accS[n] = {0.f, 0.f, 0.f, 0.f};
    const int rKb = ((lrow >> 2) << 3) + (lrow & 3);
    const short* pK = sK[cur];
    const short* pV = sV[cur];
#pragma unroll
    for (int ks = 0; ks < 2; ++ks) {
      const short8 qf = ks ? qf1 : qf0;
#pragma unroll
      for (int n = 0; n < 4; ++n) {
        const int rK = ((n >> 1) << 5) + ((n & 1) << 2) + rKb;
        const short8 kf =
            *(const short8*)(pK + rK * 64 + (((ks * 4 + lk8) ^ (rK & 7)) << 3));
        accS[n] = MFMA_BF16(kf, qf, accS[n]);
      }
    }

    float sv[4][4];
    float mx = -1e30f;
#pragma unroll
    for (int n = 0; n < 4; ++n)
#pragma unroll
      for (int r = 0; r < 4; ++r) {
        const int key = k0 + ((n >> 1) << 5) + (lk8 << 3) + ((n & 1) << 2) + r;
        float s = accS[n][r];
        s = (key > qrow) ? -1e30f : s;
        sv[n][r] = s;
        mx = fmaxf(mx, s);
      }
    mx = fmaxf(mx, __shfl_xor(mx, 16));
    mx = fmaxf(mx, __shfl_xor(mx, 32));

    const bool skip = __all(mx <= m_run + 8.0f);
    float sf = 1.f;
    if (!skip) {
      const float mnew = fmaxf(m_run, mx);
      sf = exp2f(m_run - mnew);
      m_run = mnew;
    }

    float rs = 0.f;
    unsigned int w[4][2];
#pragma unroll
    for (int n = 0; n < 4; ++n)
#pragma unroll
      for (int rp = 0; rp < 2; ++rp) {
        const float ea = exp2f(sv[n][2 * rp] - m_run);
        const float eb = exp2f(sv[n][2 * rp + 1] - m_run);
        rs += ea + eb;
        w[n][rp] = (unsigned int)(unsigned short)f2bf(ea) |
                   ((unsigned int)(unsigned short)f2bf(eb) << 16);
      }

    if (skip) {
      lsum += rs;
    } else {
      lsum = lsum * sf + rs;
      float sfq[4];
#pragma unroll
      for (int r = 0; r < 4; ++r)
        sfq[r] = __shfl(sf, (lane & 48) | (lk8 * 4 + r));
#pragma unroll
      for (int n = 0; n < 4; ++n)
#pragma unroll
        for (int r = 0; r < 4; ++r) accO[n][r] *= sfq[r];
    }

    union { short8 s; unsigned int u[4]; } paf0, paf1;
#pragma unroll
    for (int tt = 0; tt < 4; ++tt) {
      paf0.u[tt] = w[tt >> 1][tt & 1];
      paf1.u[tt] = w[2 + (tt >> 1)][tt & 1];
    }

#pragma unroll
    for (int n = 0; n < 4; ++n) {
      const int dh = n * 16 + lrow;
      const short8 vf0 = *(const short8*)(pV + dh * 64 + ((lk8 ^ (dh & 7)) << 3));
      const short8 vf1 =
          *(const short8*)(pV + dh * 64 + (((4 + lk8) ^ (dh & 7)) << 3));
      accO[n] = MFMA_BF16(paf0.s, vf0, accO[n]);
      accO[n] = MFMA_BF16(paf1.s, vf1, accO[n]);
    }

    if (t < qi) write_tile(sK[cur ^ 1], sV[cur ^ 1]);
    __syncthreads();
    cur ^= 1;
  }

  float ls = lsum;
  ls += __shfl_xor(ls, 16);
  ls += __shfl_xor(ls, 32);
  const float invown = 1.f / ls;
  float invq[4];
#pragma unroll
  for (int r = 0; r < 4; ++r)
    invq[r] = __shfl(invown, (lane & 48) | (lk8 * 4 + r));

  const int bb = bh / 12, hh = bh % 12;
#pragma unroll
  for (int n = 0; n < 4; ++n)
#pragma unroll
    for (int r = 0; r < 4; ++r) {
      const int row = q0 + wv * 16 + lk8 * 4 + r;
      const float ov = accO[n][r] * invq[r];
      o[((size_t)(bb * 1024 + row)) * 768 + hh * 64 + n * 16 + lrow] = f2bf(ov);
    }
}

// ---------------------------------------------------------------------------
extern "C" void kernel_launch(void* const* d_in, const int* in_sizes, int n_in,
                              void* d_out, int out_size, void* d_ws, size_t ws_size,
                              hipStream_t stream) {
  const int* idx = (const int*)d_in[0];
  const float* wte = (const float*)d_in[1];
  const float* wpe = (const float*)d_in[2];
  const float* ln1_g = (const float*)d_in[3];
  const float* ln1_b = (const float*)d_in[4];
  const float* wq = (const float*)d_in[5];
  const float* bq = (const float*)d_in[6];
  const float* wk = (const float*)d_in[7];
  const float* bk = (const float*)d_in[8];
  const float* wv = (const float*)d_in[9];
  const float* bv = (const float*)d_in[10];
  const float* wo = (const float*)d_in[11];
  const float* bo = (const float*)d_in[12];
  const float* ln2_g = (const float*)d_in[13];
  const float* ln2_b = (const float*)d_in[14];
  const float* w1 = (const float*)d_in[15];
  const float* b1 = (const float*)d_in[16];
  const float* w2 = (const float*)d_in[17];
  const float* b2 = (const float*)d_in[18];
  const float* lnf_g = (const float*)d_in[19];
  const float* lnf_b = (const float*)d_in[20];
  const float* lm_w = (const float*)d_in[21];
  float* out = (float*)d_out;

  char* base = (char*)d_ws;
  size_t off = 0;
  auto alloc = [&](size_t bytes) {
    char* r = base + off;
    off = (off + bytes + 255) & ~(size_t)255;
    return r;
  };
  short* lmT = (short*)alloc((size_t)50432 * 768 * 2);  // padded to 256-mult
  float* x = (float*)alloc((size_t)4096 * 768 * 4);
  short* h = (short*)alloc((size_t)4096 * 768 * 2);
  short* qb = (short*)alloc((size_t)4096 * 768 * 2);
  short* kb = (short*)alloc((size_t)4096 * 768 * 2);
  short* vtb = (short*)alloc((size_t)4096 * 768 * 2);
  short* ob = (short*)alloc((size_t)4096 * 768 * 2);
  short* ff = (short*)alloc((size_t)4096 * 3072 * 2);

  const size_t LW = 7077888;  // elements per layer weight block
  const size_t dd = (size_t)768 * 768;
  const bool big = (off + (size_t)12 * LW * 2 + 256 <= ws_size);
  short* wAll = nullptr;
  short *wqkvT = nullptr, *woT = nullptr, *w1T = nullptr, *w2T = nullptr;
  if (big) {
    wAll = (short*)alloc((size_t)12 * LW * 2);
  } else {
    wqkvT = (short*)alloc((size_t)2304 * 768 * 2);
    woT = (short*)alloc((size_t)768 * 768 * 2);
    w1T = (short*)alloc((size_t)3072 * 768 * 2);
    w2T = (short*)alloc((size_t)768 * 3072 * 2);
    if (off > ws_size) return;
  }

  const dim3 tb(32, 8);
  transpose_convert<<<dim3(1576, 24, 1), tb, 0, stream>>>(lm_w, lmT, 768, 50257, 0, 0);
  if (big) {
    transpose_convert<<<dim3(24, 24, 12), tb, 0, stream>>>(wq, wAll + 0, 768, 768, dd, LW);
    transpose_convert<<<dim3(24, 24, 12), tb, 0, stream>>>(wk, wAll + 589824, 768, 768, dd, LW);
    transpose_convert<<<dim3(24, 24, 12), tb, 0, stream>>>(wv, wAll + 1179648, 768, 768, dd, LW);
    transpose_convert<<<dim3(24, 24, 12), tb, 0, stream>>>(wo, wAll + 1769472, 768, 768, dd, LW);
    transpose_convert<<<dim3(96, 24, 12), tb, 0, stream>>>(w1, wAll + 2359296, 768, 3072,
                                                           (size_t)768 * 3072, LW);
    transpose_convert<<<dim3(24, 96, 12), tb, 0, stream>>>(w2, wAll + 4718592, 3072, 768,
                                                           (size_t)3072 * 768, LW);
  }
  embed_kernel<<<4096, 256, 0, stream>>>(idx, wte, wpe, x);

  for (int l = 0; l < 12; ++l) {
    const short *pQKV, *pWO, *pW1, *pW2;
    if (big) {
      short* wl = wAll + (size_t)l * LW;
      pQKV = wl;
      pWO = wl + 1769472;
      pW1 = wl + 2359296;
      pW2 = wl + 4718592;
    } else {
      transpose_convert<<<dim3(24, 24, 1), tb, 0, stream>>>(wq + l * dd, wqkvT, 768, 768, 0, 0);
      transpose_convert<<<dim3(24, 24, 1), tb, 0, stream>>>(wk + l * dd, wqkvT + dd, 768, 768, 0, 0);
      transpose_convert<<<dim3(24, 24, 1), tb, 0, stream>>>(wv + l * dd, wqkvT + 2 * dd, 768, 768, 0, 0);
      transpose_convert<<<dim3(24, 24, 1), tb, 0, stream>>>(wo + l * dd, woT, 768, 768, 0, 0);
      transpose_convert<<<dim3(96, 24, 1), tb, 0, stream>>>(w1 + (size_t)l * 768 * 3072, w1T, 768, 3072, 0, 0);
      transpose_convert<<<dim3(24, 96, 1), tb, 0, stream>>>(w2 + (size_t)l * 3072 * 768, w2T, 3072, 768, 0, 0);
      pQKV = wqkvT; pWO = woT; pW1 = w1T; pW2 = w2T;
    }

    ln_kernel<<<1024, 256, 0, stream>>>(x, ln1_g + l * 768, ln1_b + l * 768, h);
    gemm_kernel<128, 64, EPI_QKV><<<dim3(32, 36), 256, 0, stream>>>(
        h, pQKV, 768, bq + l * 768, bk + l * 768, bv + l * 768, nullptr, qb, kb, vtb);
    attn_kernel<<<dim3(48, 16), 256, 0, stream>>>(qb, kb, vtb, ob);
    gemm_kernel<64, 64, EPI_RESID><<<dim3(64, 12), 256, 0, stream>>>(
        ob, pWO, 768, bo + l * 768, nullptr, nullptr, x, nullptr, nullptr, nullptr);
    ln_kernel<<<1024, 256, 0, stream>>>(x, ln2_g + l * 768, ln2_b + l * 768, h);
    gemm_kernel<128, 64, EPI_GELU><<<dim3(32, 48), 256, 0, stream>>>(
        h, pW1, 768, b1 + l * 3072, nullptr, nullptr, nullptr, ff, nullptr, nullptr);
    gemm_kernel<64, 64, EPI_RESID><<<dim3(64, 12), 256, 0, stream>>>(
        ff, pW2, 3072, b2 + l * 768, nullptr, nullptr, x, nullptr, nullptr, nullptr);
  }

  ln_kernel<<<1024, 256, 0, stream>>>(x, lnf_g, lnf_b, h);
  gemm_lm_kernel<<<dim3(16, 197), 512, 0, stream>>>(h, lmT, out);
}

// Round 17
// 2827.713 us; speedup vs baseline: 1.0565x; 1.0565x over previous
//
#include <hip/hip_runtime.h>
#include <hip/hip_bf16.h>

typedef __attribute__((ext_vector_type(8))) short short8;
typedef __attribute__((ext_vector_type(4))) short short4v;
typedef __attribute__((ext_vector_type(4))) float floatx4;

#define GLD16(g, l) __builtin_amdgcn_global_load_lds( \
    (__attribute__((address_space(1))) void*)(g),      \
    (__attribute__((address_space(3))) void*)(l), 16, 0, 0)

#define MFMA_BF16(a, b, c) __builtin_amdgcn_mfma_f32_16x16x32_bf16((a), (b), (c), 0, 0, 0)

__device__ __forceinline__ short f2bf(float f) {
  union { __hip_bfloat16 h; short s; } u;
  u.h = __float2bfloat16(f);
  return u.s;
}

// ---------------------------------------------------------------------------
// transpose + fp32->bf16 convert:  in fp32 [K][N] -> out bf16 [Npad][K]
// ---------------------------------------------------------------------------
__global__ __launch_bounds__(256)
void transpose_convert(const float* __restrict__ in, short* __restrict__ out,
                       const int K, const int N, const size_t inStride,
                       const size_t outStride) {
  in += blockIdx.z * inStride;
  out += blockIdx.z * outStride;
  __shared__ float tile[32][33];
  const int n0 = blockIdx.x * 32;
  const int k0 = blockIdx.y * 32;
  const int tx = threadIdx.x;
  const int ty = threadIdx.y;
#pragma unroll
  for (int i = 0; i < 4; ++i) {
    const int kk = ty + i * 8;
    const int nn = n0 + tx;
    tile[kk][tx] = (nn < N) ? in[(size_t)(k0 + kk) * N + nn] : 0.f;
  }
  __syncthreads();
#pragma unroll
  for (int i = 0; i < 4; ++i) {
    const int nn = ty + i * 8;
    out[(size_t)(n0 + nn) * K + k0 + tx] = f2bf(tile[tx][nn]);
  }
}

// ---------------------------------------------------------------------------
__global__ __launch_bounds__(256)
void embed_kernel(const int* __restrict__ idx, const float* __restrict__ wte,
                  const float* __restrict__ wpe, float* __restrict__ x) {
  const int row = blockIdx.x;
  const int tok = idx[row];
  const int s = row & 1023;
  const float* wt = wte + (size_t)tok * 768;
  const float* wp = wpe + (size_t)s * 768;
  float* xr = x + (size_t)row * 768;
  const int c = threadIdx.x * 4;
  if (c < 768) {
    const float4 a = *(const float4*)(wt + c);
    const float4 b = *(const float4*)(wp + c);
    *(float4*)(xr + c) = float4{a.x + b.x, a.y + b.y, a.z + b.z, a.w + b.w};
  }
}

// ---------------------------------------------------------------------------
// layernorm: wave-per-row (4 rows/block), shuffle-only, short4 bf16 stores.
// ---------------------------------------------------------------------------
__global__ __launch_bounds__(256)
void ln_kernel(const float* __restrict__ x, const float* __restrict__ g,
               const float* __restrict__ b, short* __restrict__ out) {
  const int wv = threadIdx.x >> 6, lane = threadIdx.x & 63;
  const int row = blockIdx.x * 4 + wv;
  const float* xr = x + (size_t)row * 768 + lane * 12;
  const float4 a0 = *(const float4*)(xr);
  const float4 a1 = *(const float4*)(xr + 4);
  const float4 a2 = *(const float4*)(xr + 8);
  float v[12] = {a0.x, a0.y, a0.z, a0.w, a1.x, a1.y, a1.z, a1.w,
                 a2.x, a2.y, a2.z, a2.w};
  float s = 0.f;
#pragma unroll
  for (int i = 0; i < 12; ++i) s += v[i];
#pragma unroll
  for (int m = 1; m < 64; m <<= 1) s += __shfl_xor(s, m);
  const float mean = s * (1.0f / 768.0f);
  float q = 0.f;
#pragma unroll
  for (int i = 0; i < 12; ++i) {
    v[i] -= mean;
    q += v[i] * v[i];
  }
#pragma unroll
  for (int m = 1; m < 64; m <<= 1) q += __shfl_xor(q, m);
  const float inv = rsqrtf(q * (1.0f / 768.0f) + 1e-5f);

  const float* gp = g + lane * 12;
  const float* bp = b + lane * 12;
  const float4 g0 = *(const float4*)(gp);
  const float4 g1 = *(const float4*)(gp + 4);
  const float4 g2 = *(const float4*)(gp + 8);
  const float4 b0 = *(const float4*)(bp);
  const float4 b1 = *(const float4*)(bp + 4);
  const float4 b2 = *(const float4*)(bp + 8);
  const float gg[12] = {g0.x, g0.y, g0.z, g0.w, g1.x, g1.y, g1.z, g1.w,
                        g2.x, g2.y, g2.z, g2.w};
  const float bb[12] = {b0.x, b0.y, b0.z, b0.w, b1.x, b1.y, b1.z, b1.w,
                        b2.x, b2.y, b2.z, b2.w};
  short r[12];
#pragma unroll
  for (int i = 0; i < 12; ++i) r[i] = f2bf(v[i] * inv * gg[i] + bb[i]);
  short* orow = out + (size_t)row * 768 + lane * 12;
#pragma unroll
  for (int i = 0; i < 3; ++i)
    *(short4v*)(orow + i * 4) = short4v{r[i * 4], r[i * 4 + 1], r[i * 4 + 2],
                                        r[i * 4 + 3]};
}

// ---------------------------------------------------------------------------
// Layer GEMM (r12-proven): BMxBN, BK=64, unit-XOR swizzle, dbuf with
// implicit __syncthreads, hoisted incrementing stage pointers.
// ---------------------------------------------------------------------------
enum { EPI_QKV = 0, EPI_RESID = 1, EPI_GELU = 2 };

template <int BM, int BN, int EPI>
__global__ __launch_bounds__(256)
void gemm_kernel(const short* __restrict__ A, const short* __restrict__ Bt,
                 const int K,
                 const float* __restrict__ bias0, const float* __restrict__ bias1,
                 const float* __restrict__ bias2, float* __restrict__ fout,
                 short* __restrict__ bout0, short* __restrict__ bout1,
                 short* __restrict__ bout2) {
  constexpr int MF = BM / 32;
  constexpr int NF = BN / 32;
  __shared__ short sA[2][BM * 64];
  __shared__ short sB[2][BN * 64];
  const int tid = threadIdx.x;
  const int wv = tid >> 6;
  const int lane = tid & 63;
  const int lrow = lane & 15;
  const int lk8 = lane >> 4;
  const int m0 = blockIdx.x * BM;
  const int n0 = blockIdx.y * BN;
  const int wm = (wv >> 1) * (BM / 2);
  const int wn = (wv & 1) * (BN / 2);
  constexpr int MW = BM / 2 / 16;
  constexpr int NW = BN / 2 / 16;

  floatx4 acc[MW][NW];
#pragma unroll
  for (int m = 0; m < MW; ++m)
#pragma unroll
    for (int n = 0; n < NW; ++n) acc[m][n] = {0.f, 0.f, 0.f, 0.f};

  const short* pA[MF];
  const short* pB[NF];
#pragma unroll
  for (int i = 0; i < MF; ++i) {
    const int p = i * 256 + tid;
    const int rr = p >> 3, up = p & 7;
    pA[i] = A + (size_t)(m0 + rr) * K + ((up ^ (rr & 7)) << 3);
  }
#pragma unroll
  for (int i = 0; i < NF; ++i) {
    const int p = i * 256 + tid;
    const int rr = p >> 3, up = p & 7;
    pB[i] = Bt + (size_t)(n0 + rr) * K + ((up ^ (rr & 7)) << 3);
  }

  auto stage = [&](int buf) {
#pragma unroll
    for (int i = 0; i < MF; ++i) {
      GLD16(pA[i], sA[buf] + (i * 256 + wv * 64) * 8);
      pA[i] += 64;
    }
#pragma unroll
    for (int i = 0; i < NF; ++i) {
      GLD16(pB[i], sB[buf] + (i * 256 + wv * 64) * 8);
      pB[i] += 64;
    }
  };

  auto compute = [&](const short* pa, const short* pb) {
    const int xr = lrow & 7;
    short8 af[MW][2], bv[NW][2];
#pragma unroll
    for (int m = 0; m < MW; ++m) {
      const int row = (wm + m * 16 + lrow) * 64;
      af[m][0] = *(const short8*)(pa + row + ((lk8 ^ xr) << 3));
      af[m][1] = *(const short8*)(pa + row + (((4 + lk8) ^ xr) << 3));
    }
#pragma unroll
    for (int n = 0; n < NW; ++n) {
      const int row = (wn + n * 16 + lrow) * 64;
      bv[n][0] = *(const short8*)(pb + row + ((lk8 ^ xr) << 3));
      bv[n][1] = *(const short8*)(pb + row + (((4 + lk8) ^ xr) << 3));
    }
#pragma unroll
    for (int m = 0; m < MW; ++m)
#pragma unroll
      for (int n = 0; n < NW; ++n) {
        acc[m][n] = MFMA_BF16(af[m][0], bv[n][0], acc[m][n]);
        acc[m][n] = MFMA_BF16(af[m][1], bv[n][1], acc[m][n]);
      }
  };

  const int nk = K >> 6;
  stage(0);
  __syncthreads();
  int cur = 0;
  for (int kt = 0; kt < nk; ++kt) {
    if (kt + 1 < nk) stage(cur ^ 1);
    compute(sA[cur], sB[cur]);
    __syncthreads();
    cur ^= 1;
  }

#pragma unroll
  for (int m = 0; m < MW; ++m) {
#pragma unroll
    for (int n = 0; n < NW; ++n) {
#pragma unroll
      for (int r = 0; r < 4; ++r) {
        const float v = acc[m][n][r];
        const int gm = m0 + wm + m * 16 + lk8 * 4 + r;
        const int gn = n0 + wn + n * 16 + lrow;
        if (EPI == EPI_QKV) {
          const int sec = (gn >= 1536) ? 2 : (gn >= 768 ? 1 : 0);
          const int nn = gn - sec * 768;
          const int hh = nn >> 6, dh = nn & 63;
          const int bb = gm >> 10, srow = gm & 1023;
          if (sec == 0) {
            // q pre-scaled by 0.125 * log2(e) so attention can use exp2
            bout0[(((size_t)(bb * 12 + hh) * 1024 + srow) << 6) + dh] =
                f2bf((v + bias0[nn]) * 0.18033688f);
          } else if (sec == 1) {
            bout1[(((size_t)(bb * 12 + hh) * 1024 + srow) << 6) + dh] =
                f2bf(v + bias1[nn]);
          } else {
            bout2[(((size_t)(bb * 12 + hh) * 64 + dh) << 10) + srow] =
                f2bf(v + bias2[nn]);
          }
        } else if (EPI == EPI_RESID) {
          float* xp = fout + (size_t)gm * 768 + gn;
          *xp = *xp + v + bias0[gn];
        } else {  // EPI_GELU
          const float tt = v + bias0[gn];
          const float gl = 0.5f * tt * (1.f + erff(tt * 0.70710678118654752f));
          bout0[(size_t)gm * 3072 + gn] = f2bf(gl);
        }
      }
    }
  }
}

// ---------------------------------------------------------------------------
// LM-head GEMM (r12-proven best of 5 variants): 256x128, BK=64, 512 threads
// = 8 waves, single-buffered swizzled LDS (48KB), hoisted incrementing stage
// pointers, plain fp32 stores. Deep-pipeline variants (r14/r15/r16) all lost
// to this at K=768 — too few K-steps to amortize prologue/drain; cross-block
// TLP at 2 blocks/CU wins.
// ---------------------------------------------------------------------------
__global__ __launch_bounds__(512, 4)
void gemm_lm_kernel(const short* __restrict__ A, const short* __restrict__ Bt,
                    float* __restrict__ fout) {
  __shared__ short sA[256 * 64];  // 32 KB
  __shared__ short sB[128 * 64];  // 16 KB
  const int K = 768;
  const int tid = threadIdx.x;
  const int wv = tid >> 6;
  const int lane = tid & 63;
  const int lrow = lane & 15;
  const int lk8 = lane >> 4;
  const int m0 = blockIdx.x * 256;
  const int n0 = blockIdx.y * 128;
  const int wm = (wv >> 1) * 64;
  const int wn = (wv & 1) * 64;

  floatx4 acc[4][4];
#pragma unroll
  for (int m = 0; m < 4; ++m)
#pragma unroll
    for (int n = 0; n < 4; ++n) acc[m][n] = {0.f, 0.f, 0.f, 0.f};

  const short* Ab = A + (size_t)m0 * K;
  const short* Bb = Bt + (size_t)n0 * K;

  const short* pA[4];
  const short* pB[2];
#pragma unroll
  for (int i = 0; i < 4; ++i) {
    const int p = i * 512 + tid;
    const int rr = p >> 3, up = p & 7;
    pA[i] = Ab + (size_t)rr * K + ((up ^ (rr & 7)) << 3);
  }
#pragma unroll
  for (int i = 0; i < 2; ++i) {
    const int p = i * 512 + tid;
    const int rr = p >> 3, up = p & 7;
    pB[i] = Bb + (size_t)rr * K + ((up ^ (rr & 7)) << 3);
  }

  const int arow = (wm + lrow) * 64;
  const int xr = (lrow & 7);

  for (int kt = 0; kt < 12; ++kt) {
#pragma unroll
    for (int i = 0; i < 4; ++i) {
      GLD16(pA[i], sA + (i * 512 + wv * 64) * 8);
      pA[i] += 64;
    }
#pragma unroll
    for (int i = 0; i < 2; ++i) {
      GLD16(pB[i], sB + (i * 512 + wv * 64) * 8);
      pB[i] += 64;
    }
    __syncthreads();

    short8 bvv[4][2];
#pragma unroll
    for (int n = 0; n < 4; ++n) {
      const int brow = (wn + n * 16 + lrow) * 64;
      bvv[n][0] = *(const short8*)(sB + brow + ((lk8 ^ xr) << 3));
      bvv[n][1] = *(const short8*)(sB + brow + (((4 + lk8) ^ xr) << 3));
    }
#pragma unroll
    for (int m = 0; m < 4; ++m) {
      const short8 a0 = *(const short8*)(sA + arow + m * 1024 + ((lk8 ^ xr) << 3));
      const short8 a1 =
          *(const short8*)(sA + arow + m * 1024 + (((4 + lk8) ^ xr) << 3));
#pragma unroll
      for (int n = 0; n < 4; ++n) {
        acc[m][n] = MFMA_BF16(a0, bvv[n][0], acc[m][n]);
        acc[m][n] = MFMA_BF16(a1, bvv[n][1], acc[m][n]);
      }
    }
    __syncthreads();
  }

#pragma unroll
  for (int m = 0; m < 4; ++m)
#pragma unroll
    for (int n = 0; n < 4; ++n)
#pragma unroll
      for (int r = 0; r < 4; ++r) {
        const int gm = m0 + wm + m * 16 + lk8 * 4 + r;
        const int gn = n0 + wn + n * 16 + lrow;
        if (gn < 50257) fout[(size_t)gm * 50257 + gn] = acc[m][n][r];
      }
}

// ---------------------------------------------------------------------------
// flash attention (causal), swapped QK^T + dbuf async-stage + defer-max (r13).
// ---------------------------------------------------------------------------
__global__ __launch_bounds__(256)
void attn_kernel(const short* __restrict__ q, const short* __restrict__ k,
                 const short* __restrict__ vt, short* __restrict__ o) {
  __shared__ short sK[2][64 * 64];
  __shared__ short sV[2][64 * 64];
  const int bh = blockIdx.x;
  const int qi = 15 - blockIdx.y;
  const int tid = threadIdx.x;
  const int wv = tid >> 6, lane = tid & 63;
  const int lrow = lane & 15, lk8 = lane >> 4;
  const int q0 = qi * 64;
  const int qrow = q0 + wv * 16 + lrow;

  const short* qg = q + ((size_t)(bh * 1024 + qrow)) * 64 + lk8 * 8;
  const short8 qf0 = *(const short8*)qg;
  const short8 qf1 = *(const short8*)(qg + 32);

  const int e0 = tid * 8, e1 = (256 + tid) * 8;
  const int sr0 = e0 >> 6, sc0 = e0 & 63;
  const int sr1 = e1 >> 6, sc1 = e1 & 63;
  const int su0 = ((sc0 >> 3) ^ (sr0 & 7)) << 3;
  const int su1 = ((sc1 >> 3) ^ (sr1 & 7)) << 3;
  const short* kb = k + (size_t)bh * 1024 * 64;
  const short* vb = vt + (size_t)bh * 64 * 1024;

  short8 kreg0, kreg1, vreg0, vreg1;
  auto load_tile = [&](int k0) {
    kreg0 = *(const short8*)(kb + (size_t)(k0 + sr0) * 64 + sc0);
    kreg1 = *(const short8*)(kb + (size_t)(k0 + sr1) * 64 + sc1);
    vreg0 = *(const short8*)(vb + (size_t)sr0 * 1024 + k0 + sc0);
    vreg1 = *(const short8*)(vb + (size_t)sr1 * 1024 + k0 + sc1);
  };
  auto write_tile = [&](short* dK, short* dV) {
    *(short8*)(dK + sr0 * 64 + su0) = kreg0;
    *(short8*)(dK + sr1 * 64 + su1) = kreg1;
    *(short8*)(dV + sr0 * 64 + su0) = vreg0;
    *(short8*)(dV + sr1 * 64 + su1) = vreg1;
  };

  float m_run = -1e30f, lsum = 0.f;
  floatx4 accO[4];
#pragma unroll
  for (int n = 0; n < 4; ++n) accO[n] = {0.f, 0.f, 0.f, 0.f};

  load_tile(0);
  write_tile(sK[0], sV[0]);
  __syncthreads();

  int cur = 0;
  for (int t = 0; t <= qi; ++t) {
    const int k0 = t * 64;
    if (t < qi) load_tile(k0 + 64);

    floatx4 accS[4];
#pragma unroll
    for (int n = 0; n < 4; ++n) accS[n] = {0.f, 0.f, 0.f, 0.f};
    const int rKb = ((lrow >> 2) << 3) + (lrow & 3);
    const short* pK = sK[cur];
    const short* pV = sV[cur];
#pragma unroll
    for (int ks = 0; ks < 2; ++ks) {
      const short8 qf = ks ? qf1 : qf0;
#pragma unroll
      for (int n = 0; n < 4; ++n) {
        const int rK = ((n >> 1) << 5) + ((n & 1) << 2) + rKb;
        const short8 kf =
            *(const short8*)(pK + rK * 64 + (((ks * 4 + lk8) ^ (rK & 7)) << 3));
        accS[n] = MFMA_BF16(kf, qf, accS[n]);
      }
    }

    float sv[4][4];
    float mx = -1e30f;
#pragma unroll
    for (int n = 0; n < 4; ++n)
#pragma unroll
      for (int r = 0; r < 4; ++r) {
        const int key = k0 + ((n >> 1) << 5) + (lk8 << 3) + ((n & 1) << 2) + r;
        float s = accS[n][r];
        s = (key > qrow) ? -1e30f : s;
        sv[n][r] = s;
        mx = fmaxf(mx, s);
      }
    mx = fmaxf(mx, __shfl_xor(mx, 16));
    mx = fmaxf(mx, __shfl_xor(mx, 32));

    const bool skip = __all(mx <= m_run + 8.0f);
    float sf = 1.f;
    if (!skip) {
      const float mnew = fmaxf(m_run, mx);
      sf = exp2f(m_run - mnew);
      m_run = mnew;
    }

    float rs = 0.f;
    unsigned int w[4][2];
#pragma unroll
    for (int n = 0; n < 4; ++n)
#pragma unroll
      for (int rp = 0; rp < 2; ++rp) {
        const float ea = exp2f(sv[n][2 * rp] - m_run);
        const float eb = exp2f(sv[n][2 * rp + 1] - m_run);
        rs += ea + eb;
        w[n][rp] = (unsigned int)(unsigned short)f2bf(ea) |
                   ((unsigned int)(unsigned short)f2bf(eb) << 16);
      }

    if (skip) {
      lsum += rs;
    } else {
      lsum = lsum * sf + rs;
      float sfq[4];
#pragma unroll
      for (int r = 0; r < 4; ++r)
        sfq[r] = __shfl(sf, (lane & 48) | (lk8 * 4 + r));
#pragma unroll
      for (int n = 0; n < 4; ++n)
#pragma unroll
        for (int r = 0; r < 4; ++r) accO[n][r] *= sfq[r];
    }

    union { short8 s; unsigned int u[4]; } paf0, paf1;
#pragma unroll
    for (int tt = 0; tt < 4; ++tt) {
      paf0.u[tt] = w[tt >> 1][tt & 1];
      paf1.u[tt] = w[2 + (tt >> 1)][tt & 1];
    }

#pragma unroll
    for (int n = 0; n < 4; ++n) {
      const int dh = n * 16 + lrow;
      const short8 vf0 = *(const short8*)(pV + dh * 64 + ((lk8 ^ (dh & 7)) << 3));
      const short8 vf1 =
          *(const short8*)(pV + dh * 64 + (((4 + lk8) ^ (dh & 7)) << 3));
      accO[n] = MFMA_BF16(paf0.s, vf0, accO[n]);
      accO[n] = MFMA_BF16(paf1.s, vf1, accO[n]);
    }

    if (t < qi) write_tile(sK[cur ^ 1], sV[cur ^ 1]);
    __syncthreads();
    cur ^= 1;
  }

  float ls = lsum;
  ls += __shfl_xor(ls, 16);
  ls += __shfl_xor(ls, 32);
  const float invown = 1.f / ls;
  float invq[4];
#pragma unroll
  for (int r = 0; r < 4; ++r)
    invq[r] = __shfl(invown, (lane & 48) | (lk8 * 4 + r));

  const int bb = bh / 12, hh = bh % 12;
#pragma unroll
  for (int n = 0; n < 4; ++n)
#pragma unroll
    for (int r = 0; r < 4; ++r) {
      const int row = q0 + wv * 16 + lk8 * 4 + r;
      const float ov = accO[n][r] * invq[r];
      o[((size_t)(bb * 1024 + row)) * 768 + hh * 64 + n * 16 + lrow] = f2bf(ov);
    }
}

// ---------------------------------------------------------------------------
extern "C" void kernel_launch(void* const* d_in, const int* in_sizes, int n_in,
                              void* d_out, int out_size, void* d_ws, size_t ws_size,
                              hipStream_t stream) {
  const int* idx = (const int*)d_in[0];
  const float* wte = (const float*)d_in[1];
  const float* wpe = (const float*)d_in[2];
  const float* ln1_g = (const float*)d_in[3];
  const float* ln1_b = (const float*)d_in[4];
  const float* wq = (const float*)d_in[5];
  const float* bq = (const float*)d_in[6];
  const float* wk = (const float*)d_in[7];
  const float* bk = (const float*)d_in[8];
  const float* wv = (const float*)d_in[9];
  const float* bv = (const float*)d_in[10];
  const float* wo = (const float*)d_in[11];
  const float* bo = (const float*)d_in[12];
  const float* ln2_g = (const float*)d_in[13];
  const float* ln2_b = (const float*)d_in[14];
  const float* w1 = (const float*)d_in[15];
  const float* b1 = (const float*)d_in[16];
  const float* w2 = (const float*)d_in[17];
  const float* b2 = (const float*)d_in[18];
  const float* lnf_g = (const float*)d_in[19];
  const float* lnf_b = (const float*)d_in[20];
  const float* lm_w = (const float*)d_in[21];
  float* out = (float*)d_out;

  char* base = (char*)d_ws;
  size_t off = 0;
  auto alloc = [&](size_t bytes) {
    char* r = base + off;
    off = (off + bytes + 255) & ~(size_t)255;
    return r;
  };
  short* lmT = (short*)alloc((size_t)50432 * 768 * 2);
  float* x = (float*)alloc((size_t)4096 * 768 * 4);
  short* h = (short*)alloc((size_t)4096 * 768 * 2);
  short* qb = (short*)alloc((size_t)4096 * 768 * 2);
  short* kb = (short*)alloc((size_t)4096 * 768 * 2);
  short* vtb = (short*)alloc((size_t)4096 * 768 * 2);
  short* ob = (short*)alloc((size_t)4096 * 768 * 2);
  short* ff = (short*)alloc((size_t)4096 * 3072 * 2);

  const size_t LW = 7077888;  // elements per layer weight block
  const size_t dd = (size_t)768 * 768;
  const bool big = (off + (size_t)12 * LW * 2 + 256 <= ws_size);
  short* wAll = nullptr;
  short *wqkvT = nullptr, *woT = nullptr, *w1T = nullptr, *w2T = nullptr;
  if (big) {
    wAll = (short*)alloc((size_t)12 * LW * 2);
  } else {
    wqkvT = (short*)alloc((size_t)2304 * 768 * 2);
    woT = (short*)alloc((size_t)768 * 768 * 2);
    w1T = (short*)alloc((size_t)3072 * 768 * 2);
    w2T = (short*)alloc((size_t)768 * 3072 * 2);
    if (off > ws_size) return;
  }

  const dim3 tb(32, 8);
  transpose_convert<<<dim3(1576, 24, 1), tb, 0, stream>>>(lm_w, lmT, 768, 50257, 0, 0);
  if (big) {
    transpose_convert<<<dim3(24, 24, 12), tb, 0, stream>>>(wq, wAll + 0, 768, 768, dd, LW);
    transpose_convert<<<dim3(24, 24, 12), tb, 0, stream>>>(wk, wAll + 589824, 768, 768, dd, LW);
    transpose_convert<<<dim3(24, 24, 12), tb, 0, stream>>>(wv, wAll + 1179648, 768, 768, dd, LW);
    transpose_convert<<<dim3(24, 24, 12), tb, 0, stream>>>(wo, wAll + 1769472, 768, 768, dd, LW);
    transpose_convert<<<dim3(96, 24, 12), tb, 0, stream>>>(w1, wAll + 2359296, 768, 3072,
                                                           (size_t)768 * 3072, LW);
    transpose_convert<<<dim3(24, 96, 12), tb, 0, stream>>>(w2, wAll + 4718592, 3072, 768,
                                                           (size_t)3072 * 768, LW);
  }
  embed_kernel<<<4096, 256, 0, stream>>>(idx, wte, wpe, x);

  for (int l = 0; l < 12; ++l) {
    const short *pQKV, *pWO, *pW1, *pW2;
    if (big) {
      short* wl = wAll + (size_t)l * LW;
      pQKV = wl;
      pWO = wl + 1769472;
      pW1 = wl + 2359296;
      pW2 = wl + 4718592;
    } else {
      transpose_convert<<<dim3(24, 24, 1), tb, 0, stream>>>(wq + l * dd, wqkvT, 768, 768, 0, 0);
      transpose_convert<<<dim3(24, 24, 1), tb, 0, stream>>>(wk + l * dd, wqkvT + dd, 768, 768, 0, 0);
      transpose_convert<<<dim3(24, 24, 1), tb, 0, stream>>>(wv + l * dd, wqkvT + 2 * dd, 768, 768, 0, 0);
      transpose_convert<<<dim3(24, 24, 1), tb, 0, stream>>>(wo + l * dd, woT, 768, 768, 0, 0);
      transpose_convert<<<dim3(96, 24, 1), tb, 0, stream>>>(w1 + (size_t)l * 768 * 3072, w1T, 768, 3072, 0, 0);
      transpose_convert<<<dim3(24, 96, 1), tb, 0, stream>>>(w2 + (size_t)l * 3072 * 768, w2T, 3072, 768, 0, 0);
      pQKV = wqkvT; pWO = woT; pW1 = w1T; pW2 = w2T;
    }

    ln_kernel<<<1024, 256, 0, stream>>>(x, ln1_g + l * 768, ln1_b + l * 768, h);
    gemm_kernel<128, 64, EPI_QKV><<<dim3(32, 36), 256, 0, stream>>>(
        h, pQKV, 768, bq + l * 768, bk + l * 768, bv + l * 768, nullptr, qb, kb, vtb);
    attn_kernel<<<dim3(48, 16), 256, 0, stream>>>(qb, kb, vtb, ob);
    gemm_kernel<64, 64, EPI_RESID><<<dim3(64, 12), 256, 0, stream>>>(
        ob, pWO, 768, bo + l * 768, nullptr, nullptr, x, nullptr, nullptr, nullptr);
    ln_kernel<<<1024, 256, 0, stream>>>(x, ln2_g + l * 768, ln2_b + l * 768, h);
    gemm_kernel<128, 64, EPI_GELU><<<dim3(32, 48), 256, 0, stream>>>(
        h, pW1, 768, b1 + l * 3072, nullptr, nullptr, nullptr, ff, nullptr, nullptr);
    gemm_kernel<64, 64, EPI_RESID><<<dim3(64, 12), 256, 0, stream>>>(
        ff, pW2, 3072, b2 + l * 768, nullptr, nullptr, x, nullptr, nullptr, nullptr);
  }

  ln_kernel<<<1024, 256, 0, stream>>>(x, lnf_g, lnf_b, h);
  gemm_lm_kernel<<<dim3(16, 393), 512, 0, stream>>>(h, lmT, out);
}

// Round 18
// 2746.904 us; speedup vs baseline: 1.0875x; 1.0294x over previous
//
#include <hip/hip_runtime.h>
#include <hip/hip_bf16.h>

typedef __attribute__((ext_vector_type(8))) short short8;
typedef __attribute__((ext_vector_type(4))) short short4v;
typedef __attribute__((ext_vector_type(4))) float floatx4;

#define GLD16(g, l) __builtin_amdgcn_global_load_lds( \
    (__attribute__((address_space(1))) void*)(g),      \
    (__attribute__((address_space(3))) void*)(l), 16, 0, 0)

#define MFMA_BF16(a, b, c) __builtin_amdgcn_mfma_f32_16x16x32_bf16((a), (b), (c), 0, 0, 0)

__device__ __forceinline__ short f2bf(float f) {
  union { __hip_bfloat16 h; short s; } u;
  u.h = __float2bfloat16(f);
  return u.s;
}

template <bool B> struct BoolC { static constexpr bool value = B; };

// ---------------------------------------------------------------------------
// transpose + fp32->bf16 convert:  in fp32 [K][N] -> out bf16 [Npad][K]
// ---------------------------------------------------------------------------
__global__ __launch_bounds__(256)
void transpose_convert(const float* __restrict__ in, short* __restrict__ out,
                       const int K, const int N, const size_t inStride,
                       const size_t outStride) {
  in += blockIdx.z * inStride;
  out += blockIdx.z * outStride;
  __shared__ float tile[32][33];
  const int n0 = blockIdx.x * 32;
  const int k0 = blockIdx.y * 32;
  const int tx = threadIdx.x;
  const int ty = threadIdx.y;
#pragma unroll
  for (int i = 0; i < 4; ++i) {
    const int kk = ty + i * 8;
    const int nn = n0 + tx;
    tile[kk][tx] = (nn < N) ? in[(size_t)(k0 + kk) * N + nn] : 0.f;
  }
  __syncthreads();
#pragma unroll
  for (int i = 0; i < 4; ++i) {
    const int nn = ty + i * 8;
    out[(size_t)(n0 + nn) * K + k0 + tx] = f2bf(tile[tx][nn]);
  }
}

// ---------------------------------------------------------------------------
__global__ __launch_bounds__(256)
void embed_kernel(const int* __restrict__ idx, const float* __restrict__ wte,
                  const float* __restrict__ wpe, float* __restrict__ x) {
  const int row = blockIdx.x;
  const int tok = idx[row];
  const int s = row & 1023;
  const float* wt = wte + (size_t)tok * 768;
  const float* wp = wpe + (size_t)s * 768;
  float* xr = x + (size_t)row * 768;
  const int c = threadIdx.x * 4;
  if (c < 768) {
    const float4 a = *(const float4*)(wt + c);
    const float4 b = *(const float4*)(wp + c);
    *(float4*)(xr + c) = float4{a.x + b.x, a.y + b.y, a.z + b.z, a.w + b.w};
  }
}

// ---------------------------------------------------------------------------
// layernorm: wave-per-row (4 rows/block), shuffle-only, short4 bf16 stores.
// ---------------------------------------------------------------------------
__global__ __launch_bounds__(256)
void ln_kernel(const float* __restrict__ x, const float* __restrict__ g,
               const float* __restrict__ b, short* __restrict__ out) {
  const int wv = threadIdx.x >> 6, lane = threadIdx.x & 63;
  const int row = blockIdx.x * 4 + wv;
  const float* xr = x + (size_t)row * 768 + lane * 12;
  const float4 a0 = *(const float4*)(xr);
  const float4 a1 = *(const float4*)(xr + 4);
  const float4 a2 = *(const float4*)(xr + 8);
  float v[12] = {a0.x, a0.y, a0.z, a0.w, a1.x, a1.y, a1.z, a1.w,
                 a2.x, a2.y, a2.z, a2.w};
  float s = 0.f;
#pragma unroll
  for (int i = 0; i < 12; ++i) s += v[i];
#pragma unroll
  for (int m = 1; m < 64; m <<= 1) s += __shfl_xor(s, m);
  const float mean = s * (1.0f / 768.0f);
  float q = 0.f;
#pragma unroll
  for (int i = 0; i < 12; ++i) {
    v[i] -= mean;
    q += v[i] * v[i];
  }
#pragma unroll
  for (int m = 1; m < 64; m <<= 1) q += __shfl_xor(q, m);
  const float inv = rsqrtf(q * (1.0f / 768.0f) + 1e-5f);

  const float* gp = g + lane * 12;
  const float* bp = b + lane * 12;
  const float4 g0 = *(const float4*)(gp);
  const float4 g1 = *(const float4*)(gp + 4);
  const float4 g2 = *(const float4*)(gp + 8);
  const float4 b0 = *(const float4*)(bp);
  const float4 b1 = *(const float4*)(bp + 4);
  const float4 b2 = *(const float4*)(bp + 8);
  const float gg[12] = {g0.x, g0.y, g0.z, g0.w, g1.x, g1.y, g1.z, g1.w,
                        g2.x, g2.y, g2.z, g2.w};
  const float bb[12] = {b0.x, b0.y, b0.z, b0.w, b1.x, b1.y, b1.z, b1.w,
                        b2.x, b2.y, b2.z, b2.w};
  short r[12];
#pragma unroll
  for (int i = 0; i < 12; ++i) r[i] = f2bf(v[i] * inv * gg[i] + bb[i]);
  short* orow = out + (size_t)row * 768 + lane * 12;
#pragma unroll
  for (int i = 0; i < 3; ++i)
    *(short4v*)(orow + i * 4) = short4v{r[i * 4], r[i * 4 + 1], r[i * 4 + 2],
                                        r[i * 4 + 3]};
}

// ---------------------------------------------------------------------------
// Layer GEMM (r12-proven): BMxBN, BK=64, unit-XOR swizzle, dbuf with
// implicit __syncthreads, hoisted incrementing stage pointers.
// ---------------------------------------------------------------------------
enum { EPI_QKV = 0, EPI_RESID = 1, EPI_GELU = 2 };

template <int BM, int BN, int EPI>
__global__ __launch_bounds__(256)
void gemm_kernel(const short* __restrict__ A, const short* __restrict__ Bt,
                 const int K,
                 const float* __restrict__ bias0, const float* __restrict__ bias1,
                 const float* __restrict__ bias2, float* __restrict__ fout,
                 short* __restrict__ bout0, short* __restrict__ bout1,
                 short* __restrict__ bout2) {
  constexpr int MF = BM / 32;
  constexpr int NF = BN / 32;
  __shared__ short sA[2][BM * 64];
  __shared__ short sB[2][BN * 64];
  const int tid = threadIdx.x;
  const int wv = tid >> 6;
  const int lane = tid & 63;
  const int lrow = lane & 15;
  const int lk8 = lane >> 4;
  const int m0 = blockIdx.x * BM;
  const int n0 = blockIdx.y * BN;
  const int wm = (wv >> 1) * (BM / 2);
  const int wn = (wv & 1) * (BN / 2);
  constexpr int MW = BM / 2 / 16;
  constexpr int NW = BN / 2 / 16;

  floatx4 acc[MW][NW];
#pragma unroll
  for (int m = 0; m < MW; ++m)
#pragma unroll
    for (int n = 0; n < NW; ++n) acc[m][n] = {0.f, 0.f, 0.f, 0.f};

  const short* pA[MF];
  const short* pB[NF];
#pragma unroll
  for (int i = 0; i < MF; ++i) {
    const int p = i * 256 + tid;
    const int rr = p >> 3, up = p & 7;
    pA[i] = A + (size_t)(m0 + rr) * K + ((up ^ (rr & 7)) << 3);
  }
#pragma unroll
  for (int i = 0; i < NF; ++i) {
    const int p = i * 256 + tid;
    const int rr = p >> 3, up = p & 7;
    pB[i] = Bt + (size_t)(n0 + rr) * K + ((up ^ (rr & 7)) << 3);
  }

  auto stage = [&](int buf) {
#pragma unroll
    for (int i = 0; i < MF; ++i) {
      GLD16(pA[i], sA[buf] + (i * 256 + wv * 64) * 8);
      pA[i] += 64;
    }
#pragma unroll
    for (int i = 0; i < NF; ++i) {
      GLD16(pB[i], sB[buf] + (i * 256 + wv * 64) * 8);
      pB[i] += 64;
    }
  };

  auto compute = [&](const short* pa, const short* pb) {
    const int xr = lrow & 7;
    short8 af[MW][2], bv[NW][2];
#pragma unroll
    for (int m = 0; m < MW; ++m) {
      const int row = (wm + m * 16 + lrow) * 64;
      af[m][0] = *(const short8*)(pa + row + ((lk8 ^ xr) << 3));
      af[m][1] = *(const short8*)(pa + row + (((4 + lk8) ^ xr) << 3));
    }
#pragma unroll
    for (int n = 0; n < NW; ++n) {
      const int row = (wn + n * 16 + lrow) * 64;
      bv[n][0] = *(const short8*)(pb + row + ((lk8 ^ xr) << 3));
      bv[n][1] = *(const short8*)(pb + row + (((4 + lk8) ^ xr) << 3));
    }
#pragma unroll
    for (int m = 0; m < MW; ++m)
#pragma unroll
      for (int n = 0; n < NW; ++n) {
        acc[m][n] = MFMA_BF16(af[m][0], bv[n][0], acc[m][n]);
        acc[m][n] = MFMA_BF16(af[m][1], bv[n][1], acc[m][n]);
      }
  };

  const int nk = K >> 6;
  stage(0);
  __syncthreads();
  int cur = 0;
  for (int kt = 0; kt < nk; ++kt) {
    if (kt + 1 < nk) stage(cur ^ 1);
    compute(sA[cur], sB[cur]);
    __syncthreads();
    cur ^= 1;
  }

#pragma unroll
  for (int m = 0; m < MW; ++m) {
#pragma unroll
    for (int n = 0; n < NW; ++n) {
#pragma unroll
      for (int r = 0; r < 4; ++r) {
        const float v = acc[m][n][r];
        const int gm = m0 + wm + m * 16 + lk8 * 4 + r;
        const int gn = n0 + wn + n * 16 + lrow;
        if (EPI == EPI_QKV) {
          const int sec = (gn >= 1536) ? 2 : (gn >= 768 ? 1 : 0);
          const int nn = gn - sec * 768;
          const int hh = nn >> 6, dh = nn & 63;
          const int bb = gm >> 10, srow = gm & 1023;
          if (sec == 0) {
            // q pre-scaled by 0.125 * log2(e) so attention can use exp2
            bout0[(((size_t)(bb * 12 + hh) * 1024 + srow) << 6) + dh] =
                f2bf((v + bias0[nn]) * 0.18033688f);
          } else if (sec == 1) {
            bout1[(((size_t)(bb * 12 + hh) * 1024 + srow) << 6) + dh] =
                f2bf(v + bias1[nn]);
          } else {
            bout2[(((size_t)(bb * 12 + hh) * 64 + dh) << 10) + srow] =
                f2bf(v + bias2[nn]);
          }
        } else if (EPI == EPI_RESID) {
          float* xp = fout + (size_t)gm * 768 + gn;
          *xp = *xp + v + bias0[gn];
        } else {  // EPI_GELU
          const float tt = v + bias0[gn];
          const float gl = 0.5f * tt * (1.f + erff(tt * 0.70710678118654752f));
          bout0[(size_t)gm * 3072 + gn] = f2bf(gl);
        }
      }
    }
  }
}

// ---------------------------------------------------------------------------
// LM-head GEMM (r12-proven best of 5 variants): 256x128, BK=64, 512 threads
// = 8 waves, single-buffered swizzled LDS (48KB), hoisted incrementing stage
// pointers, plain fp32 stores.
// ---------------------------------------------------------------------------
__global__ __launch_bounds__(512, 4)
void gemm_lm_kernel(const short* __restrict__ A, const short* __restrict__ Bt,
                    float* __restrict__ fout) {
  __shared__ short sA[256 * 64];  // 32 KB
  __shared__ short sB[128 * 64];  // 16 KB
  const int K = 768;
  const int tid = threadIdx.x;
  const int wv = tid >> 6;
  const int lane = tid & 63;
  const int lrow = lane & 15;
  const int lk8 = lane >> 4;
  const int m0 = blockIdx.x * 256;
  const int n0 = blockIdx.y * 128;
  const int wm = (wv >> 1) * 64;
  const int wn = (wv & 1) * 64;

  floatx4 acc[4][4];
#pragma unroll
  for (int m = 0; m < 4; ++m)
#pragma unroll
    for (int n = 0; n < 4; ++n) acc[m][n] = {0.f, 0.f, 0.f, 0.f};

  const short* Ab = A + (size_t)m0 * K;
  const short* Bb = Bt + (size_t)n0 * K;

  const short* pA[4];
  const short* pB[2];
#pragma unroll
  for (int i = 0; i < 4; ++i) {
    const int p = i * 512 + tid;
    const int rr = p >> 3, up = p & 7;
    pA[i] = Ab + (size_t)rr * K + ((up ^ (rr & 7)) << 3);
  }
#pragma unroll
  for (int i = 0; i < 2; ++i) {
    const int p = i * 512 + tid;
    const int rr = p >> 3, up = p & 7;
    pB[i] = Bb + (size_t)rr * K + ((up ^ (rr & 7)) << 3);
  }

  const int arow = (wm + lrow) * 64;
  const int xr = (lrow & 7);

  for (int kt = 0; kt < 12; ++kt) {
#pragma unroll
    for (int i = 0; i < 4; ++i) {
      GLD16(pA[i], sA + (i * 512 + wv * 64) * 8);
      pA[i] += 64;
    }
#pragma unroll
    for (int i = 0; i < 2; ++i) {
      GLD16(pB[i], sB + (i * 512 + wv * 64) * 8);
      pB[i] += 64;
    }
    __syncthreads();

    short8 bvv[4][2];
#pragma unroll
    for (int n = 0; n < 4; ++n) {
      const int brow = (wn + n * 16 + lrow) * 64;
      bvv[n][0] = *(const short8*)(sB + brow + ((lk8 ^ xr) << 3));
      bvv[n][1] = *(const short8*)(sB + brow + (((4 + lk8) ^ xr) << 3));
    }
#pragma unroll
    for (int m = 0; m < 4; ++m) {
      const short8 a0 = *(const short8*)(sA + arow + m * 1024 + ((lk8 ^ xr) << 3));
      const short8 a1 =
          *(const short8*)(sA + arow + m * 1024 + (((4 + lk8) ^ xr) << 3));
#pragma unroll
      for (int n = 0; n < 4; ++n) {
        acc[m][n] = MFMA_BF16(a0, bvv[n][0], acc[m][n]);
        acc[m][n] = MFMA_BF16(a1, bvv[n][1], acc[m][n]);
      }
    }
    __syncthreads();
  }

#pragma unroll
  for (int m = 0; m < 4; ++m)
#pragma unroll
    for (int n = 0; n < 4; ++n)
#pragma unroll
      for (int r = 0; r < 4; ++r) {
        const int gm = m0 + wm + m * 16 + lk8 * 4 + r;
        const int gn = n0 + wn + n * 16 + lrow;
        if (gn < 50257) fout[(size_t)gm * 50257 + gn] = acc[m][n][r];
      }
}

// ---------------------------------------------------------------------------
// flash attention (causal), swapped QK^T + dbuf async-stage + defer-max,
// with CAUSAL PEEL: tiles t<qi run a mask-free body (no cmp/cndmask/key
// math — statically below the diagonal); only the final t==qi tile masks.
// ---------------------------------------------------------------------------
__global__ __launch_bounds__(256)
void attn_kernel(const short* __restrict__ q, const short* __restrict__ k,
                 const short* __restrict__ vt, short* __restrict__ o) {
  __shared__ short sK[2][64 * 64];
  __shared__ short sV[2][64 * 64];
  const int bh = blockIdx.x;
  const int qi = 15 - blockIdx.y;
  const int tid = threadIdx.x;
  const int wv = tid >> 6, lane = tid & 63;
  const int lrow = lane & 15, lk8 = lane >> 4;
  const int q0 = qi * 64;
  const int qrow = q0 + wv * 16 + lrow;

  const short* qg = q + ((size_t)(bh * 1024 + qrow)) * 64 + lk8 * 8;
  const short8 qf0 = *(const short8*)qg;
  const short8 qf1 = *(const short8*)(qg + 32);

  const int e0 = tid * 8, e1 = (256 + tid) * 8;
  const int sr0 = e0 >> 6, sc0 = e0 & 63;
  const int sr1 = e1 >> 6, sc1 = e1 & 63;
  const int su0 = ((sc0 >> 3) ^ (sr0 & 7)) << 3;
  const int su1 = ((sc1 >> 3) ^ (sr1 & 7)) << 3;
  const short* kb = k + (size_t)bh * 1024 * 64;
  const short* vb = vt + (size_t)bh * 64 * 1024;

  short8 kreg0, kreg1, vreg0, vreg1;
  auto load_tile = [&](int k0) {
    kreg0 = *(const short8*)(kb + (size_t)(k0 + sr0) * 64 + sc0);
    kreg1 = *(const short8*)(kb + (size_t)(k0 + sr1) * 64 + sc1);
    vreg0 = *(const short8*)(vb + (size_t)sr0 * 1024 + k0 + sc0);
    vreg1 = *(const short8*)(vb + (size_t)sr1 * 1024 + k0 + sc1);
  };
  auto write_tile = [&](short* dK, short* dV) {
    *(short8*)(dK + sr0 * 64 + su0) = kreg0;
    *(short8*)(dK + sr1 * 64 + su1) = kreg1;
    *(short8*)(dV + sr0 * 64 + su0) = vreg0;
    *(short8*)(dV + sr1 * 64 + su1) = vreg1;
  };

  float m_run = -1e30f, lsum = 0.f;
  floatx4 accO[4];
#pragma unroll
  for (int n = 0; n < 4; ++n) accO[n] = {0.f, 0.f, 0.f, 0.f};

  const int rKb = ((lrow >> 2) << 3) + (lrow & 3);

  auto tile_body = [&](int k0, const short* pK, const short* pV, auto maskc) {
    constexpr bool MASK = decltype(maskc)::value;
    floatx4 accS[4];
#pragma unroll
    for (int n = 0; n < 4; ++n) accS[n] = {0.f, 0.f, 0.f, 0.f};
#pragma unroll
    for (int ks = 0; ks < 2; ++ks) {
      const short8 qf = ks ? qf1 : qf0;
#pragma unroll
      for (int n = 0; n < 4; ++n) {
        const int rK = ((n >> 1) << 5) + ((n & 1) << 2) + rKb;
        const short8 kf =
            *(const short8*)(pK + rK * 64 + (((ks * 4 + lk8) ^ (rK & 7)) << 3));
        accS[n] = MFMA_BF16(kf, qf, accS[n]);
      }
    }

    float sv[4][4];
    float mx = -1e30f;
#pragma unroll
    for (int n = 0; n < 4; ++n)
#pragma unroll
      for (int r = 0; r < 4; ++r) {
        float s = accS[n][r];
        if (MASK) {
          const int key =
              k0 + ((n >> 1) << 5) + (lk8 << 3) + ((n & 1) << 2) + r;
          s = (key > qrow) ? -1e30f : s;
        }
        sv[n][r] = s;
        mx = fmaxf(mx, s);
      }
    mx = fmaxf(mx, __shfl_xor(mx, 16));
    mx = fmaxf(mx, __shfl_xor(mx, 32));

    const bool skip = __all(mx <= m_run + 8.0f);
    float sf = 1.f;
    if (!skip) {
      const float mnew = fmaxf(m_run, mx);
      sf = exp2f(m_run - mnew);
      m_run = mnew;
    }

    float rs = 0.f;
    unsigned int w[4][2];
#pragma unroll
    for (int n = 0; n < 4; ++n)
#pragma unroll
      for (int rp = 0; rp < 2; ++rp) {
        const float ea = exp2f(sv[n][2 * rp] - m_run);
        const float eb = exp2f(sv[n][2 * rp + 1] - m_run);
        rs += ea + eb;
        w[n][rp] = (unsigned int)(unsigned short)f2bf(ea) |
                   ((unsigned int)(unsigned short)f2bf(eb) << 16);
      }

    if (skip) {
      lsum += rs;
    } else {
      lsum = lsum * sf + rs;
      float sfq[4];
#pragma unroll
      for (int r = 0; r < 4; ++r)
        sfq[r] = __shfl(sf, (lane & 48) | (lk8 * 4 + r));
#pragma unroll
      for (int n = 0; n < 4; ++n)
#pragma unroll
        for (int r = 0; r < 4; ++r) accO[n][r] *= sfq[r];
    }

    union { short8 s; unsigned int u[4]; } paf0, paf1;
#pragma unroll
    for (int tt = 0; tt < 4; ++tt) {
      paf0.u[tt] = w[tt >> 1][tt & 1];
      paf1.u[tt] = w[2 + (tt >> 1)][tt & 1];
    }

#pragma unroll
    for (int n = 0; n < 4; ++n) {
      const int dh = n * 16 + lrow;
      const short8 vf0 = *(const short8*)(pV + dh * 64 + ((lk8 ^ (dh & 7)) << 3));
      const short8 vf1 =
          *(const short8*)(pV + dh * 64 + (((4 + lk8) ^ (dh & 7)) << 3));
      accO[n] = MFMA_BF16(paf0.s, vf0, accO[n]);
      accO[n] = MFMA_BF16(paf1.s, vf1, accO[n]);
    }
  };

  load_tile(0);
  write_tile(sK[0], sV[0]);
  __syncthreads();

  int cur = 0;
  for (int t = 0; t < qi; ++t) {
    load_tile((t + 1) * 64);                       // prefetch next tile
    tile_body(t * 64, sK[cur], sV[cur], BoolC<false>{});
    write_tile(sK[cur ^ 1], sV[cur ^ 1]);
    __syncthreads();
    cur ^= 1;
  }
  tile_body(qi * 64, sK[cur], sV[cur], BoolC<true>{});  // diagonal tile

  float ls = lsum;
  ls += __shfl_xor(ls, 16);
  ls += __shfl_xor(ls, 32);
  const float invown = 1.f / ls;
  float invq[4];
#pragma unroll
  for (int r = 0; r < 4; ++r)
    invq[r] = __shfl(invown, (lane & 48) | (lk8 * 4 + r));

  const int bb = bh / 12, hh = bh % 12;
#pragma unroll
  for (int n = 0; n < 4; ++n)
#pragma unroll
    for (int r = 0; r < 4; ++r) {
      const int row = q0 + wv * 16 + lk8 * 4 + r;
      const float ov = accO[n][r] * invq[r];
      o[((size_t)(bb * 1024 + row)) * 768 + hh * 64 + n * 16 + lrow] = f2bf(ov);
    }
}

// ---------------------------------------------------------------------------
extern "C" void kernel_launch(void* const* d_in, const int* in_sizes, int n_in,
                              void* d_out, int out_size, void* d_ws, size_t ws_size,
                              hipStream_t stream) {
  const int* idx = (const int*)d_in[0];
  const float* wte = (const float*)d_in[1];
  const float* wpe = (const float*)d_in[2];
  const float* ln1_g = (const float*)d_in[3];
  const float* ln1_b = (const float*)d_in[4];
  const float* wq = (const float*)d_in[5];
  const float* bq = (const float*)d_in[6];
  const float* wk = (const float*)d_in[7];
  const float* bk = (const float*)d_in[8];
  const float* wv = (const float*)d_in[9];
  const float* bv = (const float*)d_in[10];
  const float* wo = (const float*)d_in[11];
  const float* bo = (const float*)d_in[12];
  const float* ln2_g = (const float*)d_in[13];
  const float* ln2_b = (const float*)d_in[14];
  const float* w1 = (const float*)d_in[15];
  const float* b1 = (const float*)d_in[16];
  const float* w2 = (const float*)d_in[17];
  const float* b2 = (const float*)d_in[18];
  const float* lnf_g = (const float*)d_in[19];
  const float* lnf_b = (const float*)d_in[20];
  const float* lm_w = (const float*)d_in[21];
  float* out = (float*)d_out;

  char* base = (char*)d_ws;
  size_t off = 0;
  auto alloc = [&](size_t bytes) {
    char* r = base + off;
    off = (off + bytes + 255) & ~(size_t)255;
    return r;
  };
  short* lmT = (short*)alloc((size_t)50432 * 768 * 2);
  float* x = (float*)alloc((size_t)4096 * 768 * 4);
  short* h = (short*)alloc((size_t)4096 * 768 * 2);
  short* qb = (short*)alloc((size_t)4096 * 768 * 2);
  short* kb = (short*)alloc((size_t)4096 * 768 * 2);
  short* vtb = (short*)alloc((size_t)4096 * 768 * 2);
  short* ob = (short*)alloc((size_t)4096 * 768 * 2);
  short* ff = (short*)alloc((size_t)4096 * 3072 * 2);

  const size_t LW = 7077888;  // elements per layer weight block
  const size_t dd = (size_t)768 * 768;
  const bool big = (off + (size_t)12 * LW * 2 + 256 <= ws_size);
  short* wAll = nullptr;
  short *wqkvT = nullptr, *woT = nullptr, *w1T = nullptr, *w2T = nullptr;
  if (big) {
    wAll = (short*)alloc((size_t)12 * LW * 2);
  } else {
    wqkvT = (short*)alloc((size_t)2304 * 768 * 2);
    woT = (short*)alloc((size_t)768 * 768 * 2);
    w1T = (short*)alloc((size_t)3072 * 768 * 2);
    w2T = (short*)alloc((size_t)768 * 3072 * 2);
    if (off > ws_size) return;
  }

  const dim3 tb(32, 8);
  transpose_convert<<<dim3(1576, 24, 1), tb, 0, stream>>>(lm_w, lmT, 768, 50257, 0, 0);
  if (big) {
    transpose_convert<<<dim3(24, 24, 12), tb, 0, stream>>>(wq, wAll + 0, 768, 768, dd, LW);
    transpose_convert<<<dim3(24, 24, 12), tb, 0, stream>>>(wk, wAll + 589824, 768, 768, dd, LW);
    transpose_convert<<<dim3(24, 24, 12), tb, 0, stream>>>(wv, wAll + 1179648, 768, 768, dd, LW);
    transpose_convert<<<dim3(24, 24, 12), tb, 0, stream>>>(wo, wAll + 1769472, 768, 768, dd, LW);
    transpose_convert<<<dim3(96, 24, 12), tb, 0, stream>>>(w1, wAll + 2359296, 768, 3072,
                                                           (size_t)768 * 3072, LW);
    transpose_convert<<<dim3(24, 96, 12), tb, 0, stream>>>(w2, wAll + 4718592, 3072, 768,
                                                           (size_t)3072 * 768, LW);
  }
  embed_kernel<<<4096, 256, 0, stream>>>(idx, wte, wpe, x);

  for (int l = 0; l < 12; ++l) {
    const short *pQKV, *pWO, *pW1, *pW2;
    if (big) {
      short* wl = wAll + (size_t)l * LW;
      pQKV = wl;
      pWO = wl + 1769472;
      pW1 = wl + 2359296;
      pW2 = wl + 4718592;
    } else {
      transpose_convert<<<dim3(24, 24, 1), tb, 0, stream>>>(wq + l * dd, wqkvT, 768, 768, 0, 0);
      transpose_convert<<<dim3(24, 24, 1), tb, 0, stream>>>(wk + l * dd, wqkvT + dd, 768, 768, 0, 0);
      transpose_convert<<<dim3(24, 24, 1), tb, 0, stream>>>(wv + l * dd, wqkvT + 2 * dd, 768, 768, 0, 0);
      transpose_convert<<<dim3(24, 24, 1), tb, 0, stream>>>(wo + l * dd, woT, 768, 768, 0, 0);
      transpose_convert<<<dim3(96, 24, 1), tb, 0, stream>>>(w1 + (size_t)l * 768 * 3072, w1T, 768, 3072, 0, 0);
      transpose_convert<<<dim3(24, 96, 1), tb, 0, stream>>>(w2 + (size_t)l * 3072 * 768, w2T, 3072, 768, 0, 0);
      pQKV = wqkvT; pWO = woT; pW1 = w1T; pW2 = w2T;
    }

    ln_kernel<<<1024, 256, 0, stream>>>(x, ln1_g + l * 768, ln1_b + l * 768, h);
    gemm_kernel<128, 64, EPI_QKV><<<dim3(32, 36), 256, 0, stream>>>(
        h, pQKV, 768, bq + l * 768, bk + l * 768, bv + l * 768, nullptr, qb, kb, vtb);
    attn_kernel<<<dim3(48, 16), 256, 0, stream>>>(qb, kb, vtb, ob);
    gemm_kernel<64, 64, EPI_RESID><<<dim3(64, 12), 256, 0, stream>>>(
        ob, pWO, 768, bo + l * 768, nullptr, nullptr, x, nullptr, nullptr, nullptr);
    ln_kernel<<<1024, 256, 0, stream>>>(x, ln2_g + l * 768, ln2_b + l * 768, h);
    gemm_kernel<128, 64, EPI_GELU><<<dim3(32, 48), 256, 0, stream>>>(
        h, pW1, 768, b1 + l * 3072, nullptr, nullptr, nullptr, ff, nullptr, nullptr);
    gemm_kernel<64, 64, EPI_RESID><<<dim3(64, 12), 256, 0, stream>>>(
        ff, pW2, 3072, b2 + l * 768, nullptr, nullptr, x, nullptr, nullptr, nullptr);
  }

  ln_kernel<<<1024, 256, 0, stream>>>(x, lnf_g, lnf_b, h);
  gemm_lm_kernel<<<dim3(16, 393), 512, 0, stream>>>(h, lmT, out);
}